// Round 22
// baseline (73.956 us; speedup 1.0000x reference)
//
#include <hip/hip_runtime.h>
#include <hip/hip_fp16.h>

#define D_  160
#define H_  192
#define W_  224
#define HW_ (H_ * W_)           // 43008
#define HW2_ (HW_ / 2)          // 21504
#define N_  (D_ * H_ * W_)      // 6881280
#define NP2 (N_ / 2)            // 3440640 pairs
#define INV729 (1.0f / 729.0f)

// Buffers (all pair-indexed, pair = 2 adjacent w):
//   bufA* = uint4 per pair (c0..c3 pt0, c0..c3 pt1, fp16)
//   bufB* = dword per pair (c4 pt0, c4 pt1, fp16)
// Stage 1 (W-sums) -> bufA1/bufB1 ; stage 2 (WH-sums) -> bufA2/bufB2.

__device__ __forceinline__ unsigned pack2(float a, float b) {
    const __half2 h = __floats2half2_rn(a, b);
    return *(const unsigned*)&h;
}

// ---------------------------------------------------------------------------
// Pass 1: W-axis 9-tap sums, NO ring, NO LDS — one thread per w-pair of one
// row. 5 overlapping float2 loads per array (L1-served redundancy), 2 packed
// fp16 stores. 3.44M threads: pure load->VALU->store, massive TLP.
__global__ __launch_bounds__(256) void k_passW(const float* __restrict__ pred,
                                               const float* __restrict__ targ,
                                               uint4* __restrict__ outA,      // [NP2]
                                               unsigned* __restrict__ outB,   // [NP2]
                                               double* __restrict__ acc) {
    if (blockIdx.x == 0 && threadIdx.x == 0) *acc = 0.0;  // before k_passD
    const int pp = blockIdx.x * 256 + threadIdx.x;        // pair index < NP2
    const int row = pp / 112;                             // d*H + h
    const int ri  = pp % 112;
    const int w0  = 2 * ri;
    const float* rI = targ + (long)row * W_;              // Ii = target
    const float* rJ = pred + (long)row * W_;              // Ji = pred

    float x[10], y[10];
    #pragma unroll
    for (int m = 0; m < 5; ++m) {                         // clamped aligned float2
        const int wc  = w0 - 4 + 2 * m;
        const int wcc = wc < 0 ? 0 : (wc > W_ - 2 ? W_ - 2 : wc);
        const float2 vI = *(const float2*)(rI + wcc);
        const float2 vJ = *(const float2*)(rJ + wcc);
        x[2*m] = vI.x; x[2*m+1] = vI.y;
        y[2*m] = vJ.x; y[2*m+1] = vJ.y;
    }
    #pragma unroll
    for (int k = 0; k < 10; ++k) {                        // zero-pad edges
        if (k != 4 && k != 5) {
            const int wk = w0 - 4 + k;
            const bool v = (wk >= 0) && (wk < W_);
            x[k] = v ? x[k] : 0.f;
            y[k] = v ? y[k] : 0.f;
        }
    }
    float sI = 0.f, sJ = 0.f, sII = 0.f, sJJ = 0.f, sIJ = 0.f;
    #pragma unroll
    for (int kk = 0; kk < 9; ++kk) {
        sI += x[kk]; sJ += y[kk];
        sII = fmaf(x[kk], x[kk], sII);
        sJJ = fmaf(y[kk], y[kk], sJJ);
        sIJ = fmaf(x[kk], y[kk], sIJ);
    }
    const float tI  = sI  + x[9] - x[0];
    const float tJ  = sJ  + y[9] - y[0];
    const float tII = sII + x[9]*x[9] - x[0]*x[0];
    const float tJJ = sJJ + y[9]*y[9] - y[0]*y[0];
    const float tIJ = sIJ + x[9]*y[9] - x[0]*y[0];

    uint4 oA;
    oA.x = pack2(sI, sJ);  oA.y = pack2(sII, sJJ);
    oA.z = pack2(tI, tJ);  oA.w = pack2(tII, tJJ);
    outA[pp] = oA;
    outB[pp] = pack2(sIJ, tIJ);
}

// ---------------------------------------------------------------------------
// Pass 2: H-axis 9-tap sliding sum — k_passD structure cloned onto h.
// Thread owns a (d, w-pair) column; 2 load instrs + 2 store instrs per step;
// fp32 ring over unpacked fp16 (exact-cancel). grid = (70, 8 h-segments).
__global__ __launch_bounds__(256) void k_passH2(const uint4* __restrict__ inA,
                                                const unsigned* __restrict__ inB,
                                                uint4* __restrict__ outA,
                                                unsigned* __restrict__ outB) {
    const int HSEG2 = H_ / 8;               // 24
    const int cc = blockIdx.x * blockDim.x + threadIdx.x;   // < 17920
    const int d  = cc / 112;
    const int ri = cc % 112;
    const int h0 = blockIdx.y * HSEG2;
    const long colbase = (long)d * HW2_ + ri;   // + h*112

    float2 q[5][9], S[5];                   // .x = pt0, .y = pt1 (fp32)
    #pragma unroll
    for (int c = 0; c < 5; ++c) S[c] = make_float2(0.f, 0.f);

    #pragma unroll
    for (int k = 0; k < 9; ++k) {           // warm-up: rows h0-5 .. h0+3
        const int hh = h0 - 5 + k;          // h0+3 <= 171 < 192
        uint4 va = make_uint4(0u, 0u, 0u, 0u);
        unsigned vb = 0u;
        if (hh >= 0) {
            va = inA[colbase + (long)hh * 112];
            vb = inB[colbase + (long)hh * 112];
        }
        const float2 f01 = __half22float2(*(const __half2*)&va.x);  // sI,sJ pt0
        const float2 f23 = __half22float2(*(const __half2*)&va.y);  // sII,sJJ pt0
        const float2 g01 = __half22float2(*(const __half2*)&va.z);  // sI,sJ pt1
        const float2 g23 = __half22float2(*(const __half2*)&va.w);  // sII,sJJ pt1
        const float2 c44 = __half22float2(*(const __half2*)&vb);    // sIJ pt0,pt1
        q[0][k] = make_float2(f01.x, g01.x); S[0].x += f01.x; S[0].y += g01.x;
        q[1][k] = make_float2(f01.y, g01.y); S[1].x += f01.y; S[1].y += g01.y;
        q[2][k] = make_float2(f23.x, g23.x); S[2].x += f23.x; S[2].y += g23.x;
        q[3][k] = make_float2(f23.y, g23.y); S[3].x += f23.y; S[3].y += g23.y;
        q[4][k] = make_float2(c44.x, c44.y); S[4].x += c44.x; S[4].y += c44.y;
    }

    #pragma unroll
    for (int j = 0; j < HSEG2; ++j) {       // output row h = h0+j
        const int hh = h0 + 4 + j;
        uint4 va = make_uint4(0u, 0u, 0u, 0u);
        unsigned vb = 0u;
        if (hh < H_) {
            va = inA[colbase + (long)hh * 112];
            vb = inB[colbase + (long)hh * 112];
        }
        const float2 f01 = __half22float2(*(const __half2*)&va.x);
        const float2 f23 = __half22float2(*(const __half2*)&va.y);
        const float2 g01 = __half22float2(*(const __half2*)&va.z);
        const float2 g23 = __half22float2(*(const __half2*)&va.w);
        const float2 c44 = __half22float2(*(const __half2*)&vb);
        const float2 nv[5] = {
            make_float2(f01.x, g01.x), make_float2(f01.y, g01.y),
            make_float2(f23.x, g23.x), make_float2(f23.y, g23.y),
            make_float2(c44.x, c44.y)
        };
        const int ph = j % 9;               // compile-time (full unroll)
        #pragma unroll
        for (int c = 0; c < 5; ++c) {
            S[c].x += nv[c].x - q[c][ph].x;
            S[c].y += nv[c].y - q[c][ph].y;
            q[c][ph] = nv[c];
        }
        const long op = colbase + (long)(h0 + j) * 112;
        uint4 oA;
        oA.x = pack2(S[0].x, S[1].x); oA.y = pack2(S[2].x, S[3].x);
        oA.z = pack2(S[0].y, S[1].y); oA.w = pack2(S[2].y, S[3].y);
        outA[op] = oA;
        outB[op] = pack2(S[4].x, S[4].y);
    }
}

// ---------------------------------------------------------------------------
// Pass 3: D-axis 9-tap sliding sum + cc + reduction (unchanged, proven).
__global__ __launch_bounds__(256) void k_passD(const uint4* __restrict__ bufA,
                                               const unsigned* __restrict__ bufB,
                                               double* __restrict__ acc) {
    const int DSEG = D_ / 8;                // 20
    const int p2 = blockIdx.x * blockDim.x + threadIdx.x;   // < HW2_
    const int d0 = blockIdx.y * DSEG;

    float2 q[5][9], S[5];                   // .x = pt0, .y = pt1
    #pragma unroll
    for (int c = 0; c < 5; ++c) S[c] = make_float2(0.f, 0.f);

    #pragma unroll
    for (int k = 0; k < 9; ++k) {
        const int dd = d0 - 5 + k;          // d0+3 <= 143 < 160
        uint4 va = make_uint4(0u, 0u, 0u, 0u);
        unsigned vb = 0u;
        if (dd >= 0) {
            va = bufA[(long)dd * HW2_ + p2];
            vb = bufB[(long)dd * HW2_ + p2];
        }
        const float2 a01 = __half22float2(*(const __half2*)&va.x);
        const float2 a23 = __half22float2(*(const __half2*)&va.y);
        const float2 b01 = __half22float2(*(const __half2*)&va.z);
        const float2 b23 = __half22float2(*(const __half2*)&va.w);
        const float2 c44 = __half22float2(*(const __half2*)&vb);
        q[0][k] = make_float2(a01.x, b01.x); S[0].x += a01.x; S[0].y += b01.x;
        q[1][k] = make_float2(a01.y, b01.y); S[1].x += a01.y; S[1].y += b01.y;
        q[2][k] = make_float2(a23.x, b23.x); S[2].x += a23.x; S[2].y += b23.x;
        q[3][k] = make_float2(a23.y, b23.y); S[3].x += a23.y; S[3].y += b23.y;
        q[4][k] = make_float2(c44.x, c44.y); S[4].x += c44.x; S[4].y += c44.y;
    }

    float myacc = 0.f;
    #pragma unroll
    for (int j = 0; j < DSEG; ++j) {        // output d = d0+j
        const int dd = d0 + 4 + j;
        uint4 va = make_uint4(0u, 0u, 0u, 0u);
        unsigned vb = 0u;
        if (dd < D_) {
            va = bufA[(long)dd * HW2_ + p2];
            vb = bufB[(long)dd * HW2_ + p2];
        }
        const float2 a01 = __half22float2(*(const __half2*)&va.x);
        const float2 a23 = __half22float2(*(const __half2*)&va.y);
        const float2 b01 = __half22float2(*(const __half2*)&va.z);
        const float2 b23 = __half22float2(*(const __half2*)&va.w);
        const float2 c44 = __half22float2(*(const __half2*)&vb);
        const float2 nv[5] = {
            make_float2(a01.x, b01.x), make_float2(a01.y, b01.y),
            make_float2(a23.x, b23.x), make_float2(a23.y, b23.y),
            make_float2(c44.x, c44.y)
        };
        const int ph = j % 9;               // compile-time
        #pragma unroll
        for (int c = 0; c < 5; ++c) {
            S[c].x += nv[c].x - q[c][ph].x;
            S[c].y += nv[c].y - q[c][ph].y;
            q[c][ph] = nv[c];
        }
        #pragma unroll
        for (int e = 0; e < 2; ++e) {
            const float mu1 = (e ? S[0].y : S[0].x) * INV729;
            const float mu2 = (e ? S[1].y : S[1].x) * INV729;
            const float s1  = (e ? S[2].y : S[2].x) * INV729 - mu1 * mu1;
            const float s2  = (e ? S[3].y : S[3].x) * INV729 - mu2 * mu2;
            const float s12 = (e ? S[4].y : S[4].x) * INV729 - mu1 * mu2;
            const float den = fmaxf(s1 * s2, 1.1920929e-7f);  // finfo(f32).eps
            myacc += (s12 * s12) / den;
        }
    }

    __shared__ float red[256];
    red[threadIdx.x] = myacc;
    __syncthreads();
    #pragma unroll
    for (int s = 128; s > 0; s >>= 1) {
        if (threadIdx.x < s) red[threadIdx.x] += red[threadIdx.x + s];
        __syncthreads();
    }
    if (threadIdx.x == 0) atomicAdd(acc, (double)red[0]);
}

// ---------------------------------------------------------------------------
__global__ void k_fin(const double* __restrict__ acc, float* __restrict__ out) {
    out[0] = (float)(-(*acc) / (double)N_);
}

// ---------------------------------------------------------------------------
extern "C" void kernel_launch(void* const* d_in, const int* in_sizes, int n_in,
                              void* d_out, int out_size, void* d_ws, size_t ws_size,
                              hipStream_t stream) {
    const float* pred = (const float*)d_in[0];
    const float* targ = (const float*)d_in[1];

    char* ws = (char*)d_ws;
    uint4*    bufA1 = (uint4*)ws;                                  // NP2 x 16B
    unsigned* bufB1 = (unsigned*)(ws + (size_t)NP2 * 16);          // NP2 x 4B
    uint4*    bufA2 = (uint4*)(ws + (size_t)NP2 * 20);             // NP2 x 16B
    unsigned* bufB2 = (unsigned*)(ws + (size_t)NP2 * 36);          // NP2 x 4B
    double*   acc   = (double*)(ws + (size_t)NP2 * 40);            // 8B
    float*    out   = (float*)d_out;

    k_passW<<<NP2 / 256, 256, 0, stream>>>(pred, targ, bufA1, bufB1, acc);
    dim3 g2(17920 / 256, 8);    // 70 x 8 = 560 blocks
    k_passH2<<<g2, 256, 0, stream>>>(bufA1, bufB1, bufA2, bufB2);
    dim3 g3(HW2_ / 256, 8);     // 84 x 8 = 672 blocks
    k_passD<<<g3, 256, 0, stream>>>(bufA2, bufB2, acc);
    k_fin<<<1, 1, 0, stream>>>(acc, out);
}

// Round 23
// 55.814 us; speedup vs baseline: 1.3251x; 1.3251x over previous
//
#include <hip/hip_runtime.h>
#include <hip/hip_fp16.h>

#define D_  160
#define H_  192
#define W_  224
#define HW_ (H_ * W_)           // 43008
#define HW2_ (HW_ / 2)          // 21504
#define N_  (D_ * H_ * W_)      // 6881280
#define INV729 (1.0f / 729.0f)
#define HSEG 16
#define NSEG (H_ / HSEG)        // 12
#define NROW (HSEG + 9)         // 25 rows pushed per strip
#define UPD  (NSEG * 2)         // strip-units per d = 24 (2 halves x 12 strips)

// Intermediate: bufA = uint4 per 2 points (c0..c3 pt0, c0..c3 pt1, fp16)
//               bufB = dword per 2 points (c4 pt0, c4 pt1, fp16)

__device__ __forceinline__ unsigned pack2(float a, float b) {
    const __half2 h = __floats2half2_rn(a, b);
    return *(const unsigned*)&h;
}

// ---------------------------------------------------------------------------
// Fused W+H box-sum — DUAL d-STREAM per wave (R18/R21 base) with the step
// REORDERED: compute-read of row p comes BEFORE the staging-write of row
// p+1. DS ops complete in issue order (FIFO per wave), so in R21's order the
// read inherited the write's vmcnt dependency (a 3-step-old global load) —
// one full memory latency exposed per step. Read-first breaks that chain;
// prefetch deepened to 4 for margin. Everything else identical to R21.
__global__ __launch_bounds__(64) void k_passWH(const float* __restrict__ pred,
                                               const float* __restrict__ targ,
                                               uint4* __restrict__ outA,      // [N/2]
                                               unsigned* __restrict__ outB,   // [N/2]
                                               double* __restrict__ acc) {
    __shared__ __attribute__((aligned(16))) float2 lds[2][2][128]; // [stream][buf][entry]
    if (blockIdx.x == 0 && threadIdx.x == 0) *acc = 0.0;  // before k_passD (stream order)

    const int lane = threadIdx.x;            // one wave per block
    const int unit = blockIdx.x;             // 0 .. 80*UPD-1
    const int dp   = unit / UPD;             // 0..79
    const int rem  = unit % UPD;
    const int half = rem & 1;
    const int h0   = (rem >> 1) * HSEG;
    const long dbaseA = (long)dp * HW_;
    const long dbaseB = (long)(dp + 80) * HW_;
    const int wbase = half * 112;

    // staging roles: lanes 0-29 stage stream A, lanes 30-59 stage stream B.
    const int  sj   = (lane < 30) ? lane : lane - 30;   // chunk 0..29
    const int  w0c  = wbase - 4 + 4 * sj;
    const bool cokG = (lane < 60) && (w0c >= 0) && (w0c + 3 < W_);
    const int  wsc  = w0c < 0 ? 0 : (w0c > W_ - 4 ? W_ - 4 : w0c);
    const long sdb  = (lane < 30) ? dbaseA : dbaseB;
    const int  sstr = (lane < 30) ? 0 : 1;
    const float* gI = targ + sdb + wsc;      // Ii = target
    const float* gJ = pred + sdb + wsc;      // Ji = pred

    // fp16 H-rings: q[stream][c][ph] = half2(w-sum pt0, pt1)
    unsigned q[2][5][9];
    #pragma unroll
    for (int s = 0; s < 2; ++s)
        #pragma unroll
        for (int c = 0; c < 5; ++c)
            #pragma unroll
            for (int k = 0; k < 9; ++k) q[s][c][k] = 0u;
    float S0[2][5] = {{0,0,0,0,0},{0,0,0,0,0}};
    float S1[2][5] = {{0,0,0,0,0},{0,0,0,0,0}};

    float4 pI[4], pJ[4];                     // 4-deep prefetch (own stream)
    auto fetch = [&](int r, float4& fi, float4& fj) {
        if (r >= NROW) { fi = make_float4(0.f,0.f,0.f,0.f); fj = fi; return; }
        const int hh = h0 - 5 + r;
        const int hc = hh < 0 ? 0 : (hh >= H_ ? H_ - 1 : hh);
        float4 a = *(const float4*)(gI + (long)hc * W_);
        float4 b = *(const float4*)(gJ + (long)hc * W_);
        if (!(cokG && hh >= 0 && hh < H_)) {
            a = make_float4(0.f, 0.f, 0.f, 0.f); b = a;
        }
        fi = a; fj = b;
    };
    auto wr = [&](int row, int slot) {       // interleaved {I,J} entries
        float2* dst = &lds[sstr][row & 1][4 * sj];
        *(float4*)(dst)     = make_float4(pI[slot].x, pJ[slot].x, pI[slot].y, pJ[slot].y);
        *(float4*)(dst + 2) = make_float4(pI[slot].z, pJ[slot].z, pI[slot].w, pJ[slot].w);
    };

    if (lane < 60) {                         // prologue: rows 0..3 in flight
        fetch(0, pI[0], pJ[0]);
        fetch(1, pI[1], pJ[1]);
        fetch(2, pI[2], pJ[2]);
        fetch(3, pI[3], pJ[3]);
        wr(0, 0);                            // row 0 -> buf 0
        fetch(4, pI[0], pJ[0]);              // refill slot 0
    }

    #pragma unroll
    for (int p = 0; p < NROW; ++p) {
        // ---- (1) COMPUTE row p from buf[p&1] (written at step p-1) ----
        if (lane < 56) {
            const int ph = p % 9;            // compile-time (full unroll)
            #pragma unroll
            for (int s = 0; s < 2; ++s) {    // stream A then B — independent chains
                float x[10], y[10];
                #pragma unroll
                for (int m = 0; m < 5; ++m) {   // 16B-aligned b128: {I,J,I,J}
                    const float4 v = *(const float4*)&lds[s][p & 1][2 * lane + 2 * m];
                    x[2*m] = v.x; y[2*m] = v.y; x[2*m+1] = v.z; y[2*m+1] = v.w;
                }
                float sI = 0.f, sJ = 0.f, sII = 0.f, sJJ = 0.f, sIJ = 0.f;
                #pragma unroll
                for (int kk = 0; kk < 9; ++kk) {
                    sI  += x[kk];          sJ  += y[kk];
                    sII = fmaf(x[kk], x[kk], sII);
                    sJJ = fmaf(y[kk], y[kk], sJJ);
                    sIJ = fmaf(x[kk], y[kk], sIJ);
                }
                float w0s[5], w1s[5];
                w0s[0] = sI;  w1s[0] = sI  + x[9] - x[0];
                w0s[1] = sJ;  w1s[1] = sJ  + y[9] - y[0];
                w0s[2] = sII; w1s[2] = sII + x[9]*x[9] - x[0]*x[0];
                w0s[3] = sJJ; w1s[3] = sJJ + y[9]*y[9] - y[0]*y[0];
                w0s[4] = sIJ; w1s[4] = sIJ + x[9]*y[9] - x[0]*y[0];

                // fp16 ring update: S += unpack(pack(w)) - old (exact cancel)
                #pragma unroll
                for (int c = 0; c < 5; ++c) {
                    const unsigned nq = pack2(w0s[c], w1s[c]);
                    const float2 nf = __half22float2(*(const __half2*)&nq);
                    const float2 of = __half22float2(*(const __half2*)&q[s][c][ph]);
                    S0[s][c] += nf.x - of.x;
                    S1[s][c] += nf.y - of.y;
                    q[s][c][ph] = nq;
                }
                if (p >= 9) {                // emit row h0+p-9 for this stream
                    const long db = s ? dbaseB : dbaseA;
                    const long rb = db + (long)(h0 + p - 9) * W_;  // even
                    uint4 oA;
                    oA.x = pack2(S0[s][0], S0[s][1]); oA.y = pack2(S0[s][2], S0[s][3]);
                    oA.z = pack2(S1[s][0], S1[s][1]); oA.w = pack2(S1[s][2], S1[s][3]);
                    outA[rb / 2 + half * 56 + lane] = oA;
                    outB[rb / 2 + half * 56 + lane] = pack2(S0[s][4], S1[s][4]);
                }
            }
        }

        // ---- (2) WRITE row p+1 into buf[(p+1)&1]; (3) refill slot ----
        // FIFO safety: the read of buf[(p+1)&1] at step p-1 precedes this
        // write in program order; the read of row p+1 at step p+1 follows it.
        if (lane < 60) {
            wr(p + 1, (p + 1) & 3);
            fetch(p + 5, pI[(p + 1) & 3], pJ[(p + 1) & 3]);
        }
    }
}

// ---------------------------------------------------------------------------
// D-axis 9-tap sliding sum + cc + reduction. TWO points per thread: one b128
// (bufA) + one b32 (bufB) per d-step. Plain per-block atomicAdd, no fence.
__global__ __launch_bounds__(256) void k_passD(const uint4* __restrict__ bufA,
                                               const unsigned* __restrict__ bufB,
                                               double* __restrict__ acc) {
    const int DSEG = D_ / 8;                // 20
    const int p2 = blockIdx.x * blockDim.x + threadIdx.x;   // < HW2_
    const int d0 = blockIdx.y * DSEG;

    float2 q[5][9], S[5];                   // .x = pt0, .y = pt1
    #pragma unroll
    for (int c = 0; c < 5; ++c) S[c] = make_float2(0.f, 0.f);

    #pragma unroll
    for (int k = 0; k < 9; ++k) {
        const int dd = d0 - 5 + k;          // d0+3 <= 143 < 160
        uint4 va = make_uint4(0u, 0u, 0u, 0u);
        unsigned vb = 0u;
        if (dd >= 0) {
            va = bufA[(long)dd * HW2_ + p2];
            vb = bufB[(long)dd * HW2_ + p2];
        }
        const float2 a01 = __half22float2(*(const __half2*)&va.x);
        const float2 a23 = __half22float2(*(const __half2*)&va.y);
        const float2 b01 = __half22float2(*(const __half2*)&va.z);
        const float2 b23 = __half22float2(*(const __half2*)&va.w);
        const float2 c44 = __half22float2(*(const __half2*)&vb);
        q[0][k] = make_float2(a01.x, b01.x); S[0].x += a01.x; S[0].y += b01.x;
        q[1][k] = make_float2(a01.y, b01.y); S[1].x += a01.y; S[1].y += b01.y;
        q[2][k] = make_float2(a23.x, b23.x); S[2].x += a23.x; S[2].y += b23.x;
        q[3][k] = make_float2(a23.y, b23.y); S[3].x += a23.y; S[3].y += b23.y;
        q[4][k] = make_float2(c44.x, c44.y); S[4].x += c44.x; S[4].y += c44.y;
    }

    float myacc = 0.f;
    #pragma unroll
    for (int j = 0; j < DSEG; ++j) {        // output d = d0+j
        const int dd = d0 + 4 + j;
        uint4 va = make_uint4(0u, 0u, 0u, 0u);
        unsigned vb = 0u;
        if (dd < D_) {
            va = bufA[(long)dd * HW2_ + p2];
            vb = bufB[(long)dd * HW2_ + p2];
        }
        const float2 a01 = __half22float2(*(const __half2*)&va.x);
        const float2 a23 = __half22float2(*(const __half2*)&va.y);
        const float2 b01 = __half22float2(*(const __half2*)&va.z);
        const float2 b23 = __half22float2(*(const __half2*)&va.w);
        const float2 c44 = __half22float2(*(const __half2*)&vb);
        const float2 nv[5] = {
            make_float2(a01.x, b01.x), make_float2(a01.y, b01.y),
            make_float2(a23.x, b23.x), make_float2(a23.y, b23.y),
            make_float2(c44.x, c44.y)
        };
        const int ph = j % 9;               // compile-time
        #pragma unroll
        for (int c = 0; c < 5; ++c) {
            S[c].x += nv[c].x - q[c][ph].x;
            S[c].y += nv[c].y - q[c][ph].y;
            q[c][ph] = nv[c];
        }
        #pragma unroll
        for (int e = 0; e < 2; ++e) {
            const float mu1 = (e ? S[0].y : S[0].x) * INV729;
            const float mu2 = (e ? S[1].y : S[1].x) * INV729;
            const float s1  = (e ? S[2].y : S[2].x) * INV729 - mu1 * mu1;
            const float s2  = (e ? S[3].y : S[3].x) * INV729 - mu2 * mu2;
            const float s12 = (e ? S[4].y : S[4].x) * INV729 - mu1 * mu2;
            const float den = fmaxf(s1 * s2, 1.1920929e-7f);  // finfo(f32).eps
            myacc += (s12 * s12) / den;
        }
    }

    __shared__ float red[256];
    red[threadIdx.x] = myacc;
    __syncthreads();
    #pragma unroll
    for (int s = 128; s > 0; s >>= 1) {
        if (threadIdx.x < s) red[threadIdx.x] += red[threadIdx.x + s];
        __syncthreads();
    }
    if (threadIdx.x == 0) atomicAdd(acc, (double)red[0]);
}

// ---------------------------------------------------------------------------
__global__ void k_fin(const double* __restrict__ acc, float* __restrict__ out) {
    out[0] = (float)(-(*acc) / (double)N_);
}

// ---------------------------------------------------------------------------
extern "C" void kernel_launch(void* const* d_in, const int* in_sizes, int n_in,
                              void* d_out, int out_size, void* d_ws, size_t ws_size,
                              hipStream_t stream) {
    const float* pred = (const float*)d_in[0];
    const float* targ = (const float*)d_in[1];

    uint4*    bufA = (uint4*)d_ws;                                 // N/2 x 16B
    unsigned* bufB = (unsigned*)((char*)d_ws + (size_t)(N_ / 2) * 16);  // N/2 x 4B
    double*   acc  = (double*)((char*)d_ws + (size_t)(N_ / 2) * 16 + (size_t)(N_ / 2) * 4);
    float*    out  = (float*)d_out;

    // 1920 dual-units (80 d-pairs x 24 strip-units), 1 wave/block
    k_passWH<<<80 * UPD, 64, 0, stream>>>(pred, targ, bufA, bufB, acc);
    dim3 g3(HW2_ / 256, 8);     // 84 x 8 = 672 blocks
    k_passD<<<g3, 256, 0, stream>>>(bufA, bufB, acc);
    k_fin<<<1, 1, 0, stream>>>(acc, out);
}